// Round 1
// baseline (214.258 us; speedup 1.0000x reference)
//
#include <hip/hip_runtime.h>
#include <math.h>

#define D 128
#define H 64
#define W 100
#define R 20
#define NB 256
#define NDOC_UI (NB * R)            // 5120
#define NDOC    (2 * NDOC_UI + NB)  // 10496
#define VOCAB 50000
#define GRID 256
#define TPB  512

// e^(2x) identity tanh: exact saturation at +-1 via inf/0 in rcp.
__device__ __forceinline__ float fast_tanh(float x) {
    float u = __expf(2.0f * x);
    return 1.0f - 2.0f * __builtin_amdgcn_rcpf(1.0f + u);
}
__device__ __forceinline__ float fast_exp_tanh(float x) {
    return __expf(fast_tanh(x));
}

// fp32 -> bf16 round-to-nearest-even
__device__ __forceinline__ unsigned short f2bf(float f) {
    unsigned int b = __float_as_uint(f);
    b += 0x7fffu + ((b >> 16) & 1u);
    return (unsigned short)(b >> 16);
}

// Device-scope grid barrier. Safe because: grid=256 blocks and
// __launch_bounds__(512,4) (VGPR<=128) + 34.8KB LDS give >=2 blocks/CU
// capacity on 256 CUs -> any greedy placement keeps all 256 blocks
// resident simultaneously (512 slots >= 256 blocks). AGENT-scope
// release/acquire handles the non-coherent per-XCD L2s.
__device__ __forceinline__ void grid_barrier(unsigned* cnt) {
    __syncthreads();
    if (threadIdx.x == 0) {
        __hip_atomic_fetch_add(cnt, 1u, __ATOMIC_ACQ_REL, __HIP_MEMORY_SCOPE_AGENT);
        while (__hip_atomic_load(cnt, __ATOMIC_ACQUIRE, __HIP_MEMORY_SCOPE_AGENT) < GRID)
            __builtin_amdgcn_s_sleep(8);
    }
    __syncthreads();
}

// =============================================================================
// Fused persistent kernel: vocab_prep -> doc_embed -> pv -> attn, with three
// grid barriers. 256 blocks x 512 threads, 1 block/CU in practice.
// =============================================================================
__global__ __launch_bounds__(TPB, 4) void fused_kernel(
    const int* __restrict__ user_w, const int* __restrict__ item_w,
    const int* __restrict__ query_w,
    const float* __restrict__ emb, const float* __restrict__ w_self,
    const float* __restrict__ b_self,
    const float* __restrict__ Wq, const float* __restrict__ bq,
    const float* __restrict__ w_red, const float* __restrict__ pf,
    float* __restrict__ user_emb, float* __restrict__ item_emb,
    float* __restrict__ q_emb, float* __restrict__ pv,
    float* __restrict__ evocab, ushort* __restrict__ emb_bf,
    unsigned* __restrict__ sync_cnt,
    float* __restrict__ out)
{
    __shared__ __align__(16) float smem[128 * 68];   // 34.8 KB (pv Wb / attn)
    const int tid    = threadIdx.x;
    const int bx     = blockIdx.x;
    const int lane32 = tid & 31;

    // ---------------- Phase 1: vocab prep (grid-stride, 16 rows/block/iter) --
    {
        const int grp16 = tid >> 5;                  // 0..15
        float4 ws4 = ((const float4*)w_self)[lane32];
        float  bs  = b_self[0];
        for (int row = bx * 16 + grp16; row < VOCAB; row += GRID * 16) {
            float4 v = ((const float4*)emb)[row * 32 + lane32];
            float p = v.x * ws4.x + v.y * ws4.y + v.z * ws4.z + v.w * ws4.w;
            p += __shfl_xor(p, 16, 64);
            p += __shfl_xor(p, 8, 64);
            p += __shfl_xor(p, 4, 64);
            p += __shfl_xor(p, 2, 64);
            p += __shfl_xor(p, 1, 64);
            float e = __expf(tanhf(p + bs));         // precise tanh: 50K evals
            if (lane32 == 0) evocab[row] = e;
            ushort4 u;
            u.x = f2bf(v.x * e); u.y = f2bf(v.y * e);
            u.z = f2bf(v.z * e); u.w = f2bf(v.w * e);
            int q = lane32 >> 3;                     // d-quarter of this lane
            ushort4* dst = (ushort4*)(emb_bf + (size_t)q * VOCAB * 32);
            dst[row * 8 + (lane32 & 7)] = u;
        }
    }
    grid_barrier(&sync_cnt[0]);

    // ---------------- Phase 2: doc embed (XCD-pinned quarter tables) ---------
    // quar = (bx&7)>>1 pins each XCD's L2 to one 3.2MB quarter table (bx%8 ~ XCD).
    // Blocks of a quarter-class (64 of them) partition the 10496 docs: exactly
    // 164 docs/block, 16 lane-groups/block, 11 iterations (tail = whole waves,
    // since 164 % 16 = 4 is even -> no intra-wave divergence at bpermute).
    {
        const int quar = (bx & 7) >> 1;
        const int rb   = ((bx >> 3) << 1) | (bx & 1);   // 0..63 within class
        const int g    = tid >> 5;                      // 0..15
        const int permbase = (tid & 32) << 2;
        const int wsub = lane32 >> 2;
        const int sext = lane32 & 3;
        const uint4* eq4 = (const uint4*)(emb_bf + (size_t)quar * VOCAB * 32);

        for (int it = 0; it < 11; ++it) {
            int local = it * 16 + g;
            if (local >= 164) break;
            int doc = rb * 164 + local;

            const int* wp; float* outp;
            if (doc < NDOC_UI)        { wp = user_w + doc * W;               outp = user_emb + doc * D; }
            else if (doc < 2*NDOC_UI) { int t2 = doc - NDOC_UI;   wp = item_w  + t2 * W; outp = item_emb + t2 * D; }
            else                      { int t2 = doc - 2*NDOC_UI; wp = query_w + t2 * W; outp = q_emb    + t2 * D; }

            int wreg[4];
            #pragma unroll
            for (int k = 0; k < 4; ++k) {
                int idx = k * 32 + lane32;
                wreg[k] = wp[idx > W - 1 ? W - 1 : idx];
            }

            float ep = 0.f;
            #pragma unroll
            for (int k = 0; k < 4; ++k) {
                float e = evocab[wreg[k]];
                if (k < 3 || lane32 < 4) ep += e;
            }
            ep += __shfl_xor(ep, 16, 64);
            ep += __shfl_xor(ep, 8, 64);
            ep += __shfl_xor(ep, 4, 64);
            ep += __shfl_xor(ep, 2, 64);
            ep += __shfl_xor(ep, 1, 64);
            float inv = 1.f / ep;

            float acc[8];
            #pragma unroll
            for (int j = 0; j < 8; ++j) acc[j] = 0.f;

            #pragma unroll
            for (int c = 0; c < 2; ++c) {
                const int n  = (c == 0) ? 7 : 6;
                const int s0 = (c == 0) ? 0 : 7;
                int wid[7]; uint4 v[7];
                for (int j = 0; j < n; ++j) {
                    int s = s0 + j;
                    wid[j] = __builtin_amdgcn_ds_bpermute(
                        permbase | ((((8 * s) & 31) + wsub) << 2), wreg[s >> 2]);
                }
                for (int j = 0; j < n; ++j)
                    v[j] = eq4[(size_t)(unsigned)wid[j] * 4 + sext];
                for (int j = 0; j < n; ++j) {
                    if (s0 + j == 12 && wsub >= 4) break;   // tail mask
                    uint4 x = v[j];
                    acc[0] += __uint_as_float(x.x << 16);
                    acc[1] += __uint_as_float(x.x & 0xffff0000u);
                    acc[2] += __uint_as_float(x.y << 16);
                    acc[3] += __uint_as_float(x.y & 0xffff0000u);
                    acc[4] += __uint_as_float(x.z << 16);
                    acc[5] += __uint_as_float(x.z & 0xffff0000u);
                    acc[6] += __uint_as_float(x.w << 16);
                    acc[7] += __uint_as_float(x.w & 0xffff0000u);
                }
            }

            #pragma unroll
            for (int j = 0; j < 8; ++j) {
                acc[j] += __shfl_xor(acc[j], 4, 64);
                acc[j] += __shfl_xor(acc[j], 8, 64);
                acc[j] += __shfl_xor(acc[j], 16, 64);
            }

            if (wsub == 0) {
                float* o = outp + quar * 32 + sext * 8;
                *(float4*)o       = make_float4(acc[0]*inv, acc[1]*inv, acc[2]*inv, acc[3]*inv);
                *(float4*)(o + 4) = make_float4(acc[4]*inv, acc[5]*inv, acc[6]*inv, acc[7]*inv);
            }
        }
    }
    grid_barrier(&sync_cnt[1]);

    // ---------------- Phase 3: pv[b,d] = sum_h tanh(q@Wq+bq)*w_red -----------
    // One block = one (dd, m-half): 128 rows x 64 h, 512 threads, 4x4 tiles.
    {
        const int dd  = bx >> 1;
        const int m0g = (bx & 1) * 128;
        {
            int rrow = tid >> 4;              // 0..31
            int f4   = tid & 15;
            #pragma unroll
            for (int pass = 0; pass < 4; ++pass) {
                int k = pass * 32 + rrow;
                float4 vw = ((const float4*)Wq)[k * 2048 + dd * 16 + f4];
                *(float4*)&smem[k * 68 + f4 * 4] = vw;
            }
        }
        __syncthreads();

        int nthr = tid & 15;
        int mthr = tid >> 4;                  // 0..31
        int n0 = nthr * 4;
        const float4* q4 = (const float4*)q_emb;
        int mbase = m0g + mthr * 4;

        float acc[4][4];
        #pragma unroll
        for (int i = 0; i < 4; ++i)
            #pragma unroll
            for (int j = 0; j < 4; ++j) acc[i][j] = 0.f;

        float4 qa[4], qb[4];
        #pragma unroll
        for (int i = 0; i < 4; ++i) qa[i] = q4[(mbase + i) * 32];

        for (int k4 = 0; k4 < 32; ++k4) {
            if (k4 < 31) {
                #pragma unroll
                for (int i = 0; i < 4; ++i) qb[i] = q4[(mbase + i) * 32 + k4 + 1];
            }
            #pragma unroll
            for (int kk = 0; kk < 4; ++kk) {
                float4 wv = *(const float4*)&smem[(k4 * 4 + kk) * 68 + n0];
                #pragma unroll
                for (int i = 0; i < 4; ++i) {
                    float a = (kk == 0) ? qa[i].x : (kk == 1) ? qa[i].y
                            : (kk == 2) ? qa[i].z : qa[i].w;
                    acc[i][0] += a * wv.x;
                    acc[i][1] += a * wv.y;
                    acc[i][2] += a * wv.z;
                    acc[i][3] += a * wv.w;
                }
            }
            #pragma unroll
            for (int i = 0; i < 4; ++i) qa[i] = qb[i];
        }

        float4 bqv = ((const float4*)bq)[dd * 16 + nthr];
        float4 wrv = ((const float4*)w_red)[nthr];

        #pragma unroll
        for (int i = 0; i < 4; ++i) {
            float s = fast_tanh(acc[i][0] + bqv.x) * wrv.x
                    + fast_tanh(acc[i][1] + bqv.y) * wrv.y
                    + fast_tanh(acc[i][2] + bqv.z) * wrv.z
                    + fast_tanh(acc[i][3] + bqv.w) * wrv.w;
            s += __shfl_xor(s, 1, 64);
            s += __shfl_xor(s, 2, 64);
            s += __shfl_xor(s, 4, 64);
            s += __shfl_xor(s, 8, 64);
            if (nthr == 0) pv[(mbase + i) * 128 + dd] = s;
        }
    }
    grid_barrier(&sync_cnt[2]);

    // ---------------- Phase 4: review attention + output ---------------------
    // One block per b; thread halves handle user (set 0) / item (set 1).
    {
        const int b   = bx;
        const int set = tid >> 8;             // 0 or 1
        const int t   = tid & 255;
        const float* revg = (set == 0 ? user_emb : item_emb) + b * R * D;
        float* srev = smem + set * (R * 129);             // 2580 floats each
        float* pvl  = smem + 2 * (R * 129);               // 128
        float* ssc  = smem + 2 * (R * 129) + D + set * 32;

        for (int idx = t; idx < R * D; idx += 256)
            srev[(idx >> 7) * 129 + (idx & 127)] = revg[idx];
        if (tid < D) pvl[tid] = pv[b * D + tid];
        __syncthreads();

        if (t < R) {
            float s = 0.f;
            const float* row = &srev[t * 129];
            #pragma unroll 16
            for (int k = 0; k < D; ++k) s += row[k] * pvl[k];
            ssc[t] = s;
        }
        __syncthreads();

        float m = -1e30f;
        for (int r = 0; r < R; ++r) m = fmaxf(m, ssc[r]);
        float sum = 0.f;
        for (int r = 0; r < R; ++r) sum += __expf(ssc[r] - m);
        float inv = 1.f / sum;

        if (t < D) {
            float acc2 = 0.f;
            for (int r = 0; r < R; ++r)
                acc2 += __expf(ssc[r] - m) * inv * srev[r * 129 + t];
            if (set == 0) {
                acc2 += pf[0] * q_emb[b * D + t];
                out[b * D + t] = acc2;
            } else {
                out[NB * D + b * D + t] = acc2;
            }
        }
    }
}

// =============================================================================
// Fallback (small ws): R4-proven fp32 gather doc embed + separate pv/attn.
// =============================================================================
__global__ __launch_bounds__(256, 7) void doc_embed_fp32_kernel(
    const int* __restrict__ user_w, const int* __restrict__ item_w,
    const int* __restrict__ query_w,
    const float* __restrict__ emb, const float* __restrict__ w_self,
    const float* __restrict__ b_self,
    float* __restrict__ user_emb, float* __restrict__ item_emb,
    float* __restrict__ q_emb)
{
    int tid    = threadIdx.x;
    int lane32 = tid & 31;
    int grp    = tid >> 5;
    int doc    = blockIdx.x * 8 + grp;

    const int* wp; float* outp;
    if (doc < NDOC_UI)        { wp = user_w + doc * W;               outp = user_emb + doc * D; }
    else if (doc < 2*NDOC_UI) { int t = doc - NDOC_UI;   wp = item_w  + t * W; outp = item_emb + t * D; }
    else                      { int t = doc - 2*NDOC_UI; wp = query_w + t * W; outp = q_emb    + t * D; }

    int wreg[4];
    #pragma unroll
    for (int k = 0; k < 4; ++k) {
        int idx = k * 32 + lane32;
        wreg[k] = wp[idx > W - 1 ? W - 1 : idx];
    }

    float4 ws4 = ((const float4*)w_self)[lane32];
    float  bs  = b_self[0];
    const float4* emb4 = (const float4*)emb;
    int permbase = (tid & 32) * 4;

    float4 acc  = make_float4(0.f, 0.f, 0.f, 0.f);
    float  esum = 0.f;

    #pragma unroll
    for (int c = 0; c < 10; ++c) {
        int word[10];
        #pragma unroll
        for (int j = 0; j < 10; ++j) {
            int w = c * 10 + j;
            word[j] = __builtin_amdgcn_ds_bpermute(permbase | ((w & 31) * 4),
                                                   wreg[w >> 5]);
        }
        float4 v[10];
        #pragma unroll
        for (int j = 0; j < 10; ++j)
            v[j] = emb4[(size_t)word[j] * 32 + lane32];

        #pragma unroll
        for (int j = 0; j < 10; ++j) {
            float p = v[j].x * ws4.x + v[j].y * ws4.y + v[j].z * ws4.z + v[j].w * ws4.w;
            p += __shfl_xor(p, 16, 64);
            p += __shfl_xor(p, 8, 64);
            p += __shfl_xor(p, 4, 64);
            p += __shfl_xor(p, 2, 64);
            p += __shfl_xor(p, 1, 64);
            float e = fast_exp_tanh(p + bs);
            esum += e;
            acc.x += e * v[j].x;
            acc.y += e * v[j].y;
            acc.z += e * v[j].z;
            acc.w += e * v[j].w;
        }
    }

    float inv = 1.0f / esum;
    acc.x *= inv; acc.y *= inv; acc.z *= inv; acc.w *= inv;
    ((float4*)outp)[lane32] = acc;
}

__global__ __launch_bounds__(256) void pv_kernel(
    const float* __restrict__ q_emb, const float* __restrict__ Wq,
    const float* __restrict__ bq, const float* __restrict__ w_red,
    float* __restrict__ pv)
{
    __shared__ __align__(16) float Wb[128 * 68];

    int dd  = blockIdx.x;
    int m0g = blockIdx.y * 128;
    int tid = threadIdx.x;

    {
        int rrow = tid >> 4;
        int f4   = tid & 15;
        #pragma unroll
        for (int pass = 0; pass < 8; ++pass) {
            int k = pass * 16 + rrow;
            float4 vw = ((const float4*)Wq)[k * 2048 + dd * 16 + f4];
            *(float4*)&Wb[k * 68 + f4 * 4] = vw;
        }
    }
    __syncthreads();

    int nthr = tid & 15;
    int mthr = tid >> 4;
    int n0 = nthr * 4;
    const float4* q4 = (const float4*)q_emb;
    int mbase = (m0g + mthr * 8) * 32;

    float acc[8][4];
    #pragma unroll
    for (int i = 0; i < 8; ++i)
        #pragma unroll
        for (int j = 0; j < 4; ++j) acc[i][j] = 0.f;

    float4 qa[8], qb[8];
    #pragma unroll
    for (int i = 0; i < 8; ++i) qa[i] = q4[mbase + i * 32];

    for (int k4 = 0; k4 < 32; ++k4) {
        if (k4 < 31) {
            #pragma unroll
            for (int i = 0; i < 8; ++i) qb[i] = q4[mbase + i * 32 + k4 + 1];
        }
        #pragma unroll
        for (int kk = 0; kk < 4; ++kk) {
            float4 wv = *(const float4*)&Wb[(k4 * 4 + kk) * 68 + n0];
            #pragma unroll
            for (int i = 0; i < 8; ++i) {
                float a = (kk == 0) ? qa[i].x : (kk == 1) ? qa[i].y
                        : (kk == 2) ? qa[i].z : qa[i].w;
                acc[i][0] += a * wv.x;
                acc[i][1] += a * wv.y;
                acc[i][2] += a * wv.z;
                acc[i][3] += a * wv.w;
            }
        }
        #pragma unroll
        for (int i = 0; i < 8; ++i) qa[i] = qb[i];
    }

    float4 bqv = ((const float4*)bq)[dd * 16 + nthr];
    float4 wrv = ((const float4*)w_red)[nthr];

    #pragma unroll
    for (int i = 0; i < 8; ++i) {
        float s = fast_tanh(acc[i][0] + bqv.x) * wrv.x
                + fast_tanh(acc[i][1] + bqv.y) * wrv.y
                + fast_tanh(acc[i][2] + bqv.z) * wrv.z
                + fast_tanh(acc[i][3] + bqv.w) * wrv.w;
        s += __shfl_xor(s, 1, 64);
        s += __shfl_xor(s, 2, 64);
        s += __shfl_xor(s, 4, 64);
        s += __shfl_xor(s, 8, 64);
        if (nthr == 0) pv[(m0g + mthr * 8 + i) * 128 + dd] = s;
    }
}

__global__ __launch_bounds__(256) void attn_kernel(
    const float* __restrict__ user_emb, const float* __restrict__ item_emb,
    const float* __restrict__ q_emb, const float* __restrict__ pv,
    const float* __restrict__ pf, float* __restrict__ out)
{
    __shared__ float rev[R * 129];
    __shared__ float pvl[D];
    __shared__ float sc[R];

    int b   = blockIdx.x;
    int set = blockIdx.y;
    const float* revg = (set == 0 ? user_emb : item_emb) + b * R * D;
    int tid = threadIdx.x;

    for (int idx = tid; idx < R * D; idx += 256)
        rev[(idx >> 7) * 129 + (idx & 127)] = revg[idx];
    if (tid < D) pvl[tid] = pv[b * D + tid];
    __syncthreads();

    if (tid < R) {
        float s = 0.f;
        const float* row = &rev[tid * 129];
        #pragma unroll 16
        for (int k = 0; k < D; ++k) s += row[k] * pvl[k];
        sc[tid] = s;
    }
    __syncthreads();

    float m = -1e30f;
    for (int r = 0; r < R; ++r) m = fmaxf(m, sc[r]);
    float sum = 0.f;
    for (int r = 0; r < R; ++r) sum += __expf(sc[r] - m);
    float inv = 1.f / sum;

    if (tid < D) {
        float acc = 0.f;
        for (int r = 0; r < R; ++r)
            acc += __expf(sc[r] - m) * inv * rev[r * 129 + tid];
        if (set == 0) {
            acc += pf[0] * q_emb[b * D + tid];
            out[b * D + tid] = acc;
        } else {
            out[NB * D + b * D + tid] = acc;
        }
    }
}

extern "C" void kernel_launch(void* const* d_in, const int* in_sizes, int n_in,
                              void* d_out, int out_size, void* d_ws, size_t ws_size,
                              hipStream_t stream) {
    const int*   user_w  = (const int*)d_in[0];
    const int*   item_w  = (const int*)d_in[1];
    const int*   query_w = (const int*)d_in[2];
    const float* emb     = (const float*)d_in[3];
    const float* w_self  = (const float*)d_in[4];
    const float* b_self  = (const float*)d_in[5];
    const float* Wq      = (const float*)d_in[6];
    const float* bq      = (const float*)d_in[7];
    const float* w_red   = (const float*)d_in[8];
    const float* pf      = (const float*)d_in[9];

    float* ws       = (float*)d_ws;
    float* user_emb = ws;                          // 5120*128
    float* item_emb = user_emb + NDOC_UI * D;      // 5120*128
    float* q_emb    = item_emb + NDOC_UI * D;      // 256*128
    float* pv       = q_emb    + NB * D;           // 256*128
    float* evocab   = pv       + NB * D;           // 50000
    ushort* emb_bf  = (ushort*)(evocab + VOCAB);   // 4 quarter-tables, 12.8 MB
    unsigned* sync_cnt = (unsigned*)(emb_bf + (size_t)VOCAB * D);  // 3 barrier ctrs
    float* out      = (float*)d_out;

    const size_t need_fast =
        (size_t)(2 * NDOC_UI * D + 2 * NB * D + VOCAB) * sizeof(float)
        + (size_t)VOCAB * D * sizeof(ushort)
        + 3 * sizeof(unsigned);

    if (ws_size >= need_fast) {
        hipMemsetAsync(sync_cnt, 0, 3 * sizeof(unsigned), stream);
        fused_kernel<<<GRID, TPB, 0, stream>>>(
            user_w, item_w, query_w, emb, w_self, b_self, Wq, bq, w_red, pf,
            user_emb, item_emb, q_emb, pv, evocab, emb_bf, sync_cnt, out);
    } else {
        doc_embed_fp32_kernel<<<NDOC / 8, 256, 0, stream>>>(
            user_w, item_w, query_w, emb, w_self, b_self, user_emb, item_emb, q_emb);
        pv_kernel<<<dim3(128, 2), 256, 0, stream>>>(q_emb, Wq, bq, w_red, pv);
        attn_kernel<<<dim3(NB, 2), 256, 0, stream>>>(user_emb, item_emb, q_emb, pv, pf, out);
    }
}